// Round 1
// baseline (1434.408 us; speedup 1.0000x reference)
//
#include <hip/hip_runtime.h>
#include <cstdint>
#include <cstddef>

#define TT 8192
#define SS 32

// ---------------- helpers ----------------
__device__ __forceinline__ float rsum32(float v){
    v += __shfl_xor(v,16); v += __shfl_xor(v,8); v += __shfl_xor(v,4);
    v += __shfl_xor(v,2);  v += __shfl_xor(v,1); return v;
}
__device__ __forceinline__ float rmax32(float v){
    v = fmaxf(v,__shfl_xor(v,16)); v = fmaxf(v,__shfl_xor(v,8)); v = fmaxf(v,__shfl_xor(v,4));
    v = fmaxf(v,__shfl_xor(v,2));  v = fmaxf(v,__shfl_xor(v,1)); return v;
}
__device__ __forceinline__ void lds_read32(const float* p, float* d){
    #pragma unroll
    for (int k=0;k<8;k++){
        float4 v = ((const float4*)p)[k];
        d[4*k+0]=v.x; d[4*k+1]=v.y; d[4*k+2]=v.z; d[4*k+3]=v.w;
    }
}
__device__ __forceinline__ float arr_sum32(const float* a){
    float s0=0.f,s1=0.f,s2=0.f,s3=0.f;
    #pragma unroll
    for (int k=0;k<32;k+=4){ s0+=a[k]; s1+=a[k+1]; s2+=a[k+2]; s3+=a[k+3]; }
    return (s0+s1)+(s2+s3);
}
__device__ __forceinline__ float arr_max32(const float* a){
    float s0=a[0],s1=a[1],s2=a[2],s3=a[3];
    #pragma unroll
    for (int k=4;k<32;k+=4){ s0=fmaxf(s0,a[k]); s1=fmaxf(s1,a[k+1]); s2=fmaxf(s2,a[k+2]); s3=fmaxf(s3,a[k+3]); }
    return fmaxf(fmaxf(s0,s1),fmaxf(s2,s3));
}
__device__ __forceinline__ float dot32(const float* a, const float* b){
    float s0=0.f,s1=0.f,s2=0.f,s3=0.f;
    #pragma unroll
    for (int k=0;k<32;k+=4){
        s0=fmaf(a[k],b[k],s0); s1=fmaf(a[k+1],b[k+1],s1);
        s2=fmaf(a[k+2],b[k+2],s2); s3=fmaf(a[k+3],b[k+3],s3);
    }
    return (s0+s1)+(s2+s3);
}
__device__ __forceinline__ float gelu_exact(float v){
    return 0.5f*v*(1.0f + erff(v*0.70710678118654752440f));
}

// ---------------- prep: trans softmax, log_trans, log_init, zero LL/PS ----------------
__global__ __launch_bounds__(1024) void hmm_prep(
    const float* __restrict__ il, const float* __restrict__ tl,
    float* __restrict__ trans, float* __restrict__ lt, float* __restrict__ li,
    float* __restrict__ LL, float* __restrict__ PS)
{
    const int tid = threadIdx.x;          // 1024 = 32 rows x 32 cols
    const int c = tid & 31;
    const float v = tl[tid];
    const float m = rmax32(v);
    const float e = expf(v - m);
    const float ssum = rsum32(e);
    const float t = e / ssum;
    trans[tid] = t;
    lt[tid] = logf(t + 1e-10f);
    if (tid < 32){
        const float iv = il[c];
        const float m2 = rmax32(iv);
        const float e2 = expf(iv - m2);
        const float s2 = rsum32(e2);
        li[c] = logf(e2/s2 + 1e-10f);
        LL[c] = 0.f;
        PS[c] = 0.f;
    }
}

// ---------------- emission MLP (fused, 32 rows/block, fp32) ----------------
__global__ __launch_bounds__(256) void hmm_mlp(
    const float* __restrict__ x,
    const float* __restrict__ W1, const float* __restrict__ b1,
    const float* __restrict__ lng, const float* __restrict__ lnb,
    const float* __restrict__ W2, const float* __restrict__ b2,
    const float* __restrict__ W3, const float* __restrict__ b3,
    float* __restrict__ em_out)
{
    __shared__ float smem[16384];         // 64 KiB exactly
    float* h1s = smem;                    // [32][256]
    float* xs  = smem + 8192;             // [32][128]
    float* h2s = smem + 8192;             // [32][256] xor-swizzled, aliases xs (dead by then)

    const int tid = threadIdx.x;
    const int row0 = blockIdx.x << 5;

    {   // stage x tile
        const float4* xg = (const float4*)(x + (size_t)row0*128);
        float4* xs4 = (float4*)xs;
        #pragma unroll
        for (int l=0;l<4;l++) xs4[tid + (l<<8)] = xg[tid + (l<<8)];
    }
    __syncthreads();

    const int tc_ = tid & 31;   // col-group (8 cols)
    const int ty  = tid >> 5;   // row-group (4 rows)
    const int c0  = tc_ << 3;
    const int r0g = ty << 2;

    float acc[4][8];
    #pragma unroll
    for (int i=0;i<4;i++){
        #pragma unroll
        for (int j=0;j<8;j++) acc[i][j]=0.f;
    }

    // ---- stage 1: h1 = x @ W1 (K=128) ----
    {
        const float4* W14 = (const float4*)W1;
        #pragma unroll 2
        for (int k4=0;k4<32;k4++){
            float xv[4][4];
            #pragma unroll
            for (int i=0;i<4;i++){
                float4 t = *(const float4*)&xs[(r0g+i)*128 + (k4<<2)];
                xv[i][0]=t.x; xv[i][1]=t.y; xv[i][2]=t.z; xv[i][3]=t.w;
            }
            #pragma unroll
            for (int kk=0;kk<4;kk++){
                const int k = (k4<<2)+kk;
                const float4 wa = W14[k*64 + (tc_<<1)];
                const float4 wb = W14[k*64 + (tc_<<1) + 1];
                const float w[8] = {wa.x,wa.y,wa.z,wa.w,wb.x,wb.y,wb.z,wb.w};
                #pragma unroll
                for (int i=0;i<4;i++){
                    #pragma unroll
                    for (int j=0;j<8;j++) acc[i][j] = fmaf(xv[i][kk], w[j], acc[i][j]);
                }
            }
        }
    }

    // ---- bias + LayerNorm + GELU, write h1s ----
    {
        float4 ta = *(const float4*)&b1[c0];  float4 tb = *(const float4*)&b1[c0+4];
        const float bb[8] = {ta.x,ta.y,ta.z,ta.w,tb.x,tb.y,tb.z,tb.w};
        ta = *(const float4*)&lng[c0]; tb = *(const float4*)&lng[c0+4];
        const float gg[8] = {ta.x,ta.y,ta.z,ta.w,tb.x,tb.y,tb.z,tb.w};
        ta = *(const float4*)&lnb[c0]; tb = *(const float4*)&lnb[c0+4];
        const float be[8] = {ta.x,ta.y,ta.z,ta.w,tb.x,tb.y,tb.z,tb.w};
        #pragma unroll
        for (int i=0;i<4;i++){
            float sm=0.f;
            #pragma unroll
            for (int j=0;j<8;j++){ float v = acc[i][j]+bb[j]; acc[i][j]=v; sm+=v; }
            float sq=0.f;
            #pragma unroll
            for (int j=0;j<8;j++) sq = fmaf(acc[i][j],acc[i][j],sq);
            sm = rsum32(sm); sq = rsum32(sq);
            const float mu = sm*(1.f/256.f);
            const float var = sq*(1.f/256.f) - mu*mu;
            const float rstd = rsqrtf(var + 1e-5f);
            #pragma unroll
            for (int j=0;j<8;j++){
                float v = (acc[i][j]-mu)*rstd*gg[j] + be[j];
                acc[i][j] = gelu_exact(v);
            }
            float4 s0 = make_float4(acc[i][0],acc[i][1],acc[i][2],acc[i][3]);
            float4 s1 = make_float4(acc[i][4],acc[i][5],acc[i][6],acc[i][7]);
            *(float4*)&h1s[(r0g+i)*256 + c0]     = s0;
            *(float4*)&h1s[(r0g+i)*256 + c0 + 4] = s1;
        }
    }
    __syncthreads();

    // ---- stage 2: h2 = gelu(h1 @ W2 + b2) (K=256) ----
    #pragma unroll
    for (int i=0;i<4;i++){
        #pragma unroll
        for (int j=0;j<8;j++) acc[i][j]=0.f;
    }
    {
        const float4* W24 = (const float4*)W2;
        #pragma unroll 2
        for (int k4=0;k4<64;k4++){
            float xv[4][4];
            #pragma unroll
            for (int i=0;i<4;i++){
                float4 t = *(const float4*)&h1s[(r0g+i)*256 + (k4<<2)];
                xv[i][0]=t.x; xv[i][1]=t.y; xv[i][2]=t.z; xv[i][3]=t.w;
            }
            #pragma unroll
            for (int kk=0;kk<4;kk++){
                const int k = (k4<<2)+kk;
                const float4 wa = W24[k*64 + (tc_<<1)];
                const float4 wb = W24[k*64 + (tc_<<1) + 1];
                const float w[8] = {wa.x,wa.y,wa.z,wa.w,wb.x,wb.y,wb.z,wb.w};
                #pragma unroll
                for (int i=0;i<4;i++){
                    #pragma unroll
                    for (int j=0;j<8;j++) acc[i][j] = fmaf(xv[i][kk], w[j], acc[i][j]);
                }
            }
        }
    }
    {
        float4 ta = *(const float4*)&b2[c0];  float4 tb = *(const float4*)&b2[c0+4];
        const float bb[8] = {ta.x,ta.y,ta.z,ta.w,tb.x,tb.y,tb.z,tb.w};
        #pragma unroll
        for (int i=0;i<4;i++){
            const int r = r0g + i;
            const int sw = (r & 7) << 2;
            #pragma unroll
            for (int j=0;j<8;j++) acc[i][j] = gelu_exact(acc[i][j]+bb[j]);
            float4 s0 = make_float4(acc[i][0],acc[i][1],acc[i][2],acc[i][3]);
            float4 s1 = make_float4(acc[i][4],acc[i][5],acc[i][6],acc[i][7]);
            *(float4*)&h2s[r*256 + (c0 ^ sw)]       = s0;  // xor-swizzle kills stage-3 bank conflicts
            *(float4*)&h2s[r*256 + ((c0+4) ^ sw)]   = s1;
        }
    }
    __syncthreads();

    // ---- stage 3: logits = h2 @ W3 + b3; log_softmax; write emissions ----
    {
        const int r3 = tid >> 3;      // row 0..31
        const int cg = tid & 7;       // 4-col group
        const int sw3 = (r3 & 7) << 2;
        float a3[4] = {0.f,0.f,0.f,0.f};
        const float4* W34 = (const float4*)W3;
        #pragma unroll 2
        for (int k4=0;k4<64;k4++){
            float4 hv = *(const float4*)&h2s[r3*256 + ((k4<<2) ^ sw3)];
            const float h[4] = {hv.x,hv.y,hv.z,hv.w};
            #pragma unroll
            for (int kk=0;kk<4;kk++){
                float4 w = W34[((k4<<2)+kk)*8 + cg];
                a3[0]=fmaf(h[kk],w.x,a3[0]); a3[1]=fmaf(h[kk],w.y,a3[1]);
                a3[2]=fmaf(h[kk],w.z,a3[2]); a3[3]=fmaf(h[kk],w.w,a3[3]);
            }
        }
        float4 b3v = ((const float4*)b3)[cg];
        a3[0]+=b3v.x; a3[1]+=b3v.y; a3[2]+=b3v.z; a3[3]+=b3v.w;
        float m = fmaxf(fmaxf(a3[0],a3[1]),fmaxf(a3[2],a3[3]));
        m = fmaxf(m,__shfl_xor(m,4)); m = fmaxf(m,__shfl_xor(m,2)); m = fmaxf(m,__shfl_xor(m,1));
        float se = expf(a3[0]-m)+expf(a3[1]-m)+expf(a3[2]-m)+expf(a3[3]-m);
        se += __shfl_xor(se,4); se += __shfl_xor(se,2); se += __shfl_xor(se,1);
        const float lz = m + logf(se);
        float4 o = make_float4(a3[0]-lz, a3[1]-lz, a3[2]-lz, a3[3]-lz);
        *(float4*)&em_out[((size_t)(row0+r3))*32 + (cg<<2)] = o;
    }
}

// ---------------- forward scan: chunked (L=64, warm=64), linear domain, per-step normalize ----------------
// state_probs[t] = normalized alpha; LL = sum of log(step sums) accumulated via atomics.
__global__ __launch_bounds__(256) void hmm_fwd(
    const float* __restrict__ em, const float* __restrict__ trans,
    const float* __restrict__ li, float* __restrict__ sp, float* __restrict__ LL)
{
    __shared__ float Ab[8][32];
    const int lane = threadIdx.x & 63;
    const int s = lane & 31;
    const int ci = ((threadIdx.x >> 6) << 1) | (lane >> 5);
    const int cid = (blockIdx.x << 3) + ci;   // 4096 chunks
    const int b = cid >> 7;
    const int c = cid & 127;
    const int t0 = c << 6;

    float tc[32];
    #pragma unroll
    for (int k=0;k<32;k++) tc[k] = trans[(k<<5) + s];
    float* A = Ab[ci];
    const float* emb = em + (size_t)b*(TT*SS);
    const float li_s = li[s];

    A[s] = 0.03125f;
    asm volatile("s_waitcnt lgkmcnt(0)" ::: "memory");
    __builtin_amdgcn_wave_barrier();

    float sig = 0.f;
    float araw_prev = 0.f;

    const int tws = t0 - 64;
    float pe[8];
    #pragma unroll
    for (int j=0;j<8;j++){ int tt = tws + j; tt = tt < 0 ? 0 : tt; pe[j] = emb[(tt<<5) + s]; }

    // warm-up (64 steps; c==0 runs harmless t=0 repeats, overridden at main i==0)
    #pragma unroll 1
    for (int g=0; g<8; g++){
        float ce[8];
        #pragma unroll
        for (int j=0;j<8;j++) ce[j] = pe[j];
        #pragma unroll
        for (int j=0;j<8;j++){ int tt = tws + ((g+1)<<3) + j; tt = tt < 0 ? 0 : tt; pe[j] = emb[(tt<<5) + s]; }
        #pragma unroll
        for (int j=0;j<8;j++){
            float Av[32];
            lds_read32(A, Av);
            const float sum = arr_sum32(Av);
            const float val = dot32(Av, tc);
            const float rs = 1.0f / sum;
            const float e = __expf(ce[j]);
            const float araw = val * rs * e;
            __builtin_amdgcn_wave_barrier();
            A[s] = araw;
            asm volatile("s_waitcnt lgkmcnt(0)" ::: "memory");
            __builtin_amdgcn_wave_barrier();
        }
    }

    // main (64 steps); store for step t-1 happens at step t (sum known then)
    #pragma unroll 1
    for (int g=0; g<8; g++){
        float ce[8];
        #pragma unroll
        for (int j=0;j<8;j++) ce[j] = pe[j];
        #pragma unroll
        for (int j=0;j<8;j++){ int tt = t0 + ((g+1)<<3) + j; tt = tt > (TT-1) ? (TT-1) : tt; pe[j] = emb[(tt<<5) + s]; }
        #pragma unroll
        for (int j=0;j<8;j++){
            const int i = (g<<3) + j;
            const int t = t0 + i;
            float Av[32];
            lds_read32(A, Av);
            const float sum = arr_sum32(Av);
            const float val = dot32(Av, tc);
            const float rs = 1.0f / sum;
            if (i > 0){
                sp[((size_t)b*TT + (t-1))*SS + s] = araw_prev * rs;
                sig += __logf(sum);
            }
            const float e = __expf(ce[j]);
            float araw = val * rs * e;
            if (c == 0 && i == 0) araw = __expf(li_s) * e;   // exact init alpha0
            __builtin_amdgcn_wave_barrier();
            A[s] = araw;
            asm volatile("s_waitcnt lgkmcnt(0)" ::: "memory");
            __builtin_amdgcn_wave_barrier();
            araw_prev = araw;
        }
    }
    {   // epilogue: finish last step of region
        float Av[32];
        lds_read32(A, Av);
        const float sum = arr_sum32(Av);
        const float rs = 1.0f / sum;
        sp[((size_t)b*TT + (t0+63))*SS + s] = araw_prev * rs;
        sig += __logf(sum);
    }
    if (s == 0) atomicAdd(&LL[b], sig);
}

// ---------------- Viterbi scan: chunked (L=64, warm=128), max-plus with re-centering ----------------
__global__ __launch_bounds__(256) void hmm_vit(
    const float* __restrict__ em, const float* __restrict__ lt,
    const float* __restrict__ li, unsigned char* __restrict__ bps,
    float* __restrict__ PS, int* __restrict__ last_state)
{
    __shared__ float Vb[8][32];
    const int lane = threadIdx.x & 63;
    const int s = lane & 31;
    const int ci = ((threadIdx.x >> 6) << 1) | (lane >> 5);
    const int cid = (blockIdx.x << 3) + ci;
    const int b = cid >> 7;
    const int c = cid & 127;
    const int t0 = c << 6;

    float ltc[32];
    #pragma unroll
    for (int k=0;k<32;k++) ltc[k] = lt[(k<<5) + s];
    float* V = Vb[ci];
    const float* emb = em + (size_t)b*(TT*SS);
    const float li_s = li[s];

    V[s] = 0.f;
    asm volatile("s_waitcnt lgkmcnt(0)" ::: "memory");
    __builtin_amdgcn_wave_barrier();

    float delta = 0.f;

    const int tws = t0 - 128;
    float pe[8];
    #pragma unroll
    for (int j=0;j<8;j++){ int tt = tws + j; tt = tt < 0 ? 0 : tt; pe[j] = emb[(tt<<5) + s]; }

    // warm-up (128 steps; periodic re-center, no logging)
    #pragma unroll 1
    for (int g=0; g<16; g++){
        float ce[8];
        #pragma unroll
        for (int j=0;j<8;j++) ce[j] = pe[j];
        #pragma unroll
        for (int j=0;j<8;j++){ int tt = tws + ((g+1)<<3) + j; tt = tt < 0 ? 0 : tt; pe[j] = emb[(tt<<5) + s]; }
        #pragma unroll
        for (int j=0;j<8;j++){
            float Vv[32];
            lds_read32(V, Vv);
            float b0=-3.0e38f,b1v=-3.0e38f,b2v=-3.0e38f,b3v=-3.0e38f;
            #pragma unroll
            for (int k=0;k<32;k+=4){
                b0  = fmaxf(b0,  Vv[k]+ltc[k]);
                b1v = fmaxf(b1v, Vv[k+1]+ltc[k+1]);
                b2v = fmaxf(b2v, Vv[k+2]+ltc[k+2]);
                b3v = fmaxf(b3v, Vv[k+3]+ltc[k+3]);
            }
            float v = fmaxf(fmaxf(b0,b1v),fmaxf(b2v,b3v)) + ce[j];
            if (j == 7) v -= arr_max32(Vv);
            __builtin_amdgcn_wave_barrier();
            V[s] = v;
            asm volatile("s_waitcnt lgkmcnt(0)" ::: "memory");
            __builtin_amdgcn_wave_barrier();
        }
    }
    {   // forced exact centering at warm exit (max becomes exactly 0)
        float Vv[32];
        lds_read32(V, Vv);
        const float mm = arr_max32(Vv);
        __builtin_amdgcn_wave_barrier();
        V[s] = Vv[s] - mm;
        asm volatile("s_waitcnt lgkmcnt(0)" ::: "memory");
        __builtin_amdgcn_wave_barrier();
    }

    // main (64 steps): argmax backpointers + logged re-centering every 8 steps
    #pragma unroll 1
    for (int g=0; g<8; g++){
        float ce[8];
        #pragma unroll
        for (int j=0;j<8;j++) ce[j] = pe[j];
        #pragma unroll
        for (int j=0;j<8;j++){ int tt = t0 + ((g+1)<<3) + j; tt = tt > (TT-1) ? (TT-1) : tt; pe[j] = emb[(tt<<5) + s]; }
        #pragma unroll
        for (int j=0;j<8;j++){
            const int i = (g<<3) + j;
            const int t = t0 + i;
            float Vv[32];
            lds_read32(V, Vv);
            float B0=Vv[0]+ltc[0], B1=Vv[1]+ltc[1], B2=Vv[2]+ltc[2], B3=Vv[3]+ltc[3];
            int I0=0,I1=1,I2=2,I3=3;
            #pragma unroll
            for (int k=4;k<32;k+=4){
                float q0=Vv[k]+ltc[k];     if (q0>B0){B0=q0;I0=k;}
                float q1=Vv[k+1]+ltc[k+1]; if (q1>B1){B1=q1;I1=k+1;}
                float q2=Vv[k+2]+ltc[k+2]; if (q2>B2){B2=q2;I2=k+2;}
                float q3=Vv[k+3]+ltc[k+3]; if (q3>B3){B3=q3;I3=k+3;}
            }
            float best = B0; int bi = I0;
            if (B1>best || (B1==best && I1<bi)){best=B1;bi=I1;}
            if (B2>best || (B2==best && I2<bi)){best=B2;bi=I2;}
            if (B3>best || (B3==best && I3<bi)){best=B3;bi=I3;}
            float mmc = 0.f;
            if (j == 0){ mmc = arr_max32(Vv); delta += mmc; }  // exactly 0 at i==0
            float v;
            if (c == 0 && i == 0){
                v = li_s + ce[j];                               // exact init vit0
            } else {
                v = best + ce[j] - mmc;
                bps[((size_t)b*TT + t)*SS + s] = (unsigned char)bi;
            }
            __builtin_amdgcn_wave_barrier();
            V[s] = v;
            asm volatile("s_waitcnt lgkmcnt(0)" ::: "memory");
            __builtin_amdgcn_wave_barrier();
        }
    }
    {   // epilogue: close the telescoping sum; last chunk emits last_state
        float Vv[32];
        lds_read32(V, Vv);
        const float mm = arr_max32(Vv);
        delta += mm;
        if (c == 127){
            float best = Vv[0]; int bi = 0;
            #pragma unroll
            for (int k=1;k<32;k++){ if (Vv[k] > best){ best = Vv[k]; bi = k; } }
            if (s == 0) last_state[b] = bi;
        }
        if (s == 0) atomicAdd(&PS[b], delta);
    }
}

// ---------------- backtrace phase 1: per-256-step chunk, walk all 32 end-states, record history ----------------
__global__ __launch_bounds__(64) void hmm_btc(
    const unsigned char* __restrict__ bps, unsigned char* __restrict__ pos,
    unsigned char* __restrict__ gmap)
{
    __shared__ unsigned char bp[8192];
    const int b = blockIdx.x >> 5;
    const int cb = blockIdx.x & 31;
    const int tbase = cb << 8;
    {
        const uint4* src = (const uint4*)(bps + ((size_t)b*TT + tbase)*SS);
        uint4* dst = (uint4*)bp;
        #pragma unroll
        for (int l=0;l<8;l++) dst[threadIdx.x + (l<<6)] = src[threadIdx.x + (l<<6)];
    }
    __syncthreads();
    if (threadIdx.x < 32){
        int cur = threadIdx.x;
        unsigned char* pc = pos + (((size_t)b<<5) + cb)*8192;
        #pragma unroll 1
        for (int t=255; t>=0; t--){
            pc[(t<<5) + threadIdx.x] = (unsigned char)cur;
            if ((tbase + t) >= 1) cur = bp[(t<<5) + cur];
        }
        gmap[(((b<<5) + cb)<<5) + threadIdx.x] = (unsigned char)cur;
    }
}

// ---------------- backtrace phase 2: serial boundary composition (tiny) ----------------
__global__ __launch_bounds__(256) void hmm_btb(
    const unsigned char* __restrict__ gmap, const int* __restrict__ last_state,
    unsigned char* __restrict__ e_tab)
{
    __shared__ unsigned char gl[32768];
    #pragma unroll
    for (int l=0;l<8;l++) ((uint4*)gl)[threadIdx.x + (l<<8)] = ((const uint4*)gmap)[threadIdx.x + (l<<8)];
    __syncthreads();
    if (threadIdx.x < 32){
        const int b = threadIdx.x;
        int s = last_state[b];
        #pragma unroll 1
        for (int cb=31; cb>=1; cb--){
            e_tab[(b<<5)+cb] = (unsigned char)s;
            s = gl[(((b<<5)+cb)<<5) + s];
        }
        e_tab[b<<5] = (unsigned char)s;
    }
}

// ---------------- backtrace phase 3: parallel gather of the path ----------------
__global__ __launch_bounds__(256) void hmm_btf(
    const unsigned char* __restrict__ pos, const unsigned char* __restrict__ e_tab,
    float* __restrict__ path)
{
    const int i = blockIdx.x*256 + threadIdx.x;   // over B*T
    const int b = i >> 13;
    const int t = i & (TT-1);
    const int cb = t >> 8;
    const int e = e_tab[(b<<5) + cb];
    const unsigned char v = pos[((((size_t)b<<5) + cb)<<13) + ((t & 255)<<5) + e];
    path[i] = (float)v;
}

// ---------------- launcher ----------------
extern "C" void kernel_launch(void* const* d_in, const int* in_sizes, int n_in,
                              void* d_out, int out_size, void* d_ws, size_t ws_size,
                              hipStream_t stream)
{
    const float* x   = (const float*)d_in[0];
    const float* il  = (const float*)d_in[1];
    const float* tl  = (const float*)d_in[2];
    const float* W1  = (const float*)d_in[3];
    const float* b1  = (const float*)d_in[4];
    const float* lng = (const float*)d_in[5];
    const float* lnb = (const float*)d_in[6];
    const float* W2  = (const float*)d_in[7];
    const float* b2  = (const float*)d_in[8];
    const float* W3  = (const float*)d_in[9];
    const float* b3  = (const float*)d_in[10];

    float* out   = (float*)d_out;
    float* em    = out;                    // (B,T,S)  8388608
    float* sp    = out + 8388608;          // (B,T,S)  8388608
    float* LL    = out + 16777216;         // (B,)     32
    float* trans = out + 16777248;         // (S,S)    1024
    float* path  = out + 16778272;         // (B,T)    262144
    float* PS    = out + 17040416;         // (B,)     32

    char* wsb = (char*)d_ws;
    float* lt            = (float*)(wsb);                       // 4096 B
    float* li            = (float*)(wsb + 4096);                // 128 B
    int* last_state      = (int*)(wsb + 4224);                  // 128 B
    unsigned char* e_tab = (unsigned char*)(wsb + 4352);        // 1024 B
    unsigned char* bps   = (unsigned char*)(wsb + 8192);        // 8 MiB
    unsigned char* pos   = (unsigned char*)(wsb + 8192 + 8388608);   // 8 MiB
    unsigned char* gmap  = (unsigned char*)(wsb + 8192 + 16777216);  // 32 KiB

    hmm_prep<<<1, 1024, 0, stream>>>(il, tl, trans, lt, li, LL, PS);
    hmm_mlp<<<8192, 256, 0, stream>>>(x, W1, b1, lng, lnb, W2, b2, W3, b3, em);
    hmm_fwd<<<512, 256, 0, stream>>>(em, trans, li, sp, LL);
    hmm_vit<<<512, 256, 0, stream>>>(em, lt, li, bps, PS, last_state);
    hmm_btc<<<1024, 64, 0, stream>>>(bps, pos, gmap);
    hmm_btb<<<1, 256, 0, stream>>>(gmap, last_state, e_tab);
    hmm_btf<<<1024, 256, 0, stream>>>(pos, e_tab, path);
}

// Round 3
// 1431.843 us; speedup vs baseline: 1.0018x; 1.0018x over previous
//
#include <hip/hip_runtime.h>
#include <cstdint>
#include <cstddef>

#define TT 8192
#define SS 32

// ---------------- helpers ----------------
__device__ __forceinline__ float rsum32(float v){
    v += __shfl_xor(v,16); v += __shfl_xor(v,8); v += __shfl_xor(v,4);
    v += __shfl_xor(v,2);  v += __shfl_xor(v,1); return v;
}
__device__ __forceinline__ float rmax32(float v){
    v = fmaxf(v,__shfl_xor(v,16)); v = fmaxf(v,__shfl_xor(v,8)); v = fmaxf(v,__shfl_xor(v,4));
    v = fmaxf(v,__shfl_xor(v,2));  v = fmaxf(v,__shfl_xor(v,1)); return v;
}
__device__ __forceinline__ float rsum64(float v){
    v += __shfl_xor(v,32); v += __shfl_xor(v,16); v += __shfl_xor(v,8);
    v += __shfl_xor(v,4);  v += __shfl_xor(v,2);  v += __shfl_xor(v,1); return v;
}
__device__ __forceinline__ void lds_read32(const float* p, float* d){
    #pragma unroll
    for (int k=0;k<8;k++){
        float4 v = ((const float4*)p)[k];
        d[4*k+0]=v.x; d[4*k+1]=v.y; d[4*k+2]=v.z; d[4*k+3]=v.w;
    }
}
__device__ __forceinline__ float arr_sum32(const float* a){
    float s0=0.f,s1=0.f,s2=0.f,s3=0.f;
    #pragma unroll
    for (int k=0;k<32;k+=4){ s0+=a[k]; s1+=a[k+1]; s2+=a[k+2]; s3+=a[k+3]; }
    return (s0+s1)+(s2+s3);
}
__device__ __forceinline__ float arr_max32(const float* a){
    float s0=a[0],s1=a[1],s2=a[2],s3=a[3];
    #pragma unroll
    for (int k=4;k<32;k+=4){ s0=fmaxf(s0,a[k]); s1=fmaxf(s1,a[k+1]); s2=fmaxf(s2,a[k+2]); s3=fmaxf(s3,a[k+3]); }
    return fmaxf(fmaxf(s0,s1),fmaxf(s2,s3));
}
__device__ __forceinline__ float dot32(const float* a, const float* b){
    float s0=0.f,s1=0.f,s2=0.f,s3=0.f;
    #pragma unroll
    for (int k=0;k<32;k+=4){
        s0=fmaf(a[k],b[k],s0); s1=fmaf(a[k+1],b[k+1],s1);
        s2=fmaf(a[k+2],b[k+2],s2); s3=fmaf(a[k+3],b[k+3],s3);
    }
    return (s0+s1)+(s2+s3);
}
__device__ __forceinline__ float gelu_exact(float v){
    return 0.5f*v*(1.0f + erff(v*0.70710678118654752440f));
}

// ---------------- prep: trans softmax, log_trans, log_init, zero LL/PS ----------------
__global__ __launch_bounds__(1024) void hmm_prep(
    const float* __restrict__ il, const float* __restrict__ tl,
    float* __restrict__ trans, float* __restrict__ lt, float* __restrict__ li,
    float* __restrict__ LL, float* __restrict__ PS)
{
    const int tid = threadIdx.x;          // 1024 = 32 rows x 32 cols
    const int c = tid & 31;
    const float v = tl[tid];
    const float m = rmax32(v);
    const float e = expf(v - m);
    const float ssum = rsum32(e);
    const float t = e / ssum;
    trans[tid] = t;
    lt[tid] = logf(t + 1e-10f);
    if (tid < 32){
        const float iv = il[c];
        const float m2 = rmax32(iv);
        const float e2 = expf(iv - m2);
        const float s2 = rsum32(e2);
        li[c] = logf(e2/s2 + 1e-10f);
        LL[c] = 0.f;
        PS[c] = 0.f;
    }
}

// ---------------- emission MLP: wave-private, 8 rows/wave, 4 cols/lane, no barriers ----------------
__global__ __launch_bounds__(256, 5) void hmm_mlp(
    const float* __restrict__ x,
    const float* __restrict__ W1, const float* __restrict__ b1,
    const float* __restrict__ lng, const float* __restrict__ lnb,
    const float* __restrict__ W2, const float* __restrict__ b2,
    const float* __restrict__ W3, const float* __restrict__ b3,
    float* __restrict__ em_out)
{
    __shared__ float hbuf[8192];          // 32 KiB, wave-private 8 KiB stripes
    const int tid  = threadIdx.x;
    const int lane = tid & 63;
    const int wv   = tid >> 6;
    const int row0 = blockIdx.x << 5;     // 32 rows per block
    const int r0   = wv << 3;             // this wave's first tile-row
    const int c0   = lane << 2;           // this lane's 4 columns

    // uniform (SGPR) x row base -> scalar loads
    const int r0u = __builtin_amdgcn_readfirstlane(r0);
    const float* xw = x + ((size_t)(row0 + r0u) << 7);

    float acc[8][4];
    #pragma unroll
    for (int i=0;i<8;i++){ acc[i][0]=0.f; acc[i][1]=0.f; acc[i][2]=0.f; acc[i][3]=0.f; }

    // ---- stage 1: h1 = x @ W1 (K=128) ----
    #pragma unroll 2
    for (int k4=0;k4<32;k4++){
        const float4 w0 = *(const float4*)&W1[((k4<<2)+0)*256 + c0];
        const float4 w1 = *(const float4*)&W1[((k4<<2)+1)*256 + c0];
        const float4 w2 = *(const float4*)&W1[((k4<<2)+2)*256 + c0];
        const float4 w3 = *(const float4*)&W1[((k4<<2)+3)*256 + c0];
        #pragma unroll
        for (int i=0;i<8;i++){
            const float4 xv = *(const float4*)(xw + (i<<7) + (k4<<2));
            acc[i][0]=fmaf(xv.x,w0.x,acc[i][0]); acc[i][1]=fmaf(xv.x,w0.y,acc[i][1]);
            acc[i][2]=fmaf(xv.x,w0.z,acc[i][2]); acc[i][3]=fmaf(xv.x,w0.w,acc[i][3]);
            acc[i][0]=fmaf(xv.y,w1.x,acc[i][0]); acc[i][1]=fmaf(xv.y,w1.y,acc[i][1]);
            acc[i][2]=fmaf(xv.y,w1.z,acc[i][2]); acc[i][3]=fmaf(xv.y,w1.w,acc[i][3]);
            acc[i][0]=fmaf(xv.z,w2.x,acc[i][0]); acc[i][1]=fmaf(xv.z,w2.y,acc[i][1]);
            acc[i][2]=fmaf(xv.z,w2.z,acc[i][2]); acc[i][3]=fmaf(xv.z,w2.w,acc[i][3]);
            acc[i][0]=fmaf(xv.w,w3.x,acc[i][0]); acc[i][1]=fmaf(xv.w,w3.y,acc[i][1]);
            acc[i][2]=fmaf(xv.w,w3.z,acc[i][2]); acc[i][3]=fmaf(xv.w,w3.w,acc[i][3]);
        }
    }

    // ---- bias + LayerNorm + GELU -> h1 (LDS, wave-private rows) ----
    {
        const float4 bb = *(const float4*)&b1[c0];
        const float4 gg = *(const float4*)&lng[c0];
        const float4 be = *(const float4*)&lnb[c0];
        #pragma unroll
        for (int i=0;i<8;i++){
            float a0=acc[i][0]+bb.x, a1=acc[i][1]+bb.y, a2=acc[i][2]+bb.z, a3=acc[i][3]+bb.w;
            float sm = (a0+a1)+(a2+a3);
            float sq = fmaf(a0,a0,fmaf(a1,a1,fmaf(a2,a2,a3*a3)));
            sm = rsum64(sm); sq = rsum64(sq);
            const float mu   = sm*(1.f/256.f);
            const float var  = sq*(1.f/256.f) - mu*mu;
            const float rstd = rsqrtf(var + 1e-5f);
            a0 = gelu_exact((a0-mu)*rstd*gg.x + be.x);
            a1 = gelu_exact((a1-mu)*rstd*gg.y + be.y);
            a2 = gelu_exact((a2-mu)*rstd*gg.z + be.z);
            a3 = gelu_exact((a3-mu)*rstd*gg.w + be.w);
            *(float4*)&hbuf[(r0+i)*256 + c0] = make_float4(a0,a1,a2,a3);
        }
    }

    // ---- stage 2: h2 = gelu(h1 @ W2 + b2) (K=256), h1 read as wave-uniform broadcast ----
    #pragma unroll
    for (int i=0;i<8;i++){ acc[i][0]=0.f; acc[i][1]=0.f; acc[i][2]=0.f; acc[i][3]=0.f; }
    #pragma unroll 2
    for (int k4=0;k4<64;k4++){
        const float4 w0 = *(const float4*)&W2[((k4<<2)+0)*256 + c0];
        const float4 w1 = *(const float4*)&W2[((k4<<2)+1)*256 + c0];
        const float4 w2 = *(const float4*)&W2[((k4<<2)+2)*256 + c0];
        const float4 w3 = *(const float4*)&W2[((k4<<2)+3)*256 + c0];
        #pragma unroll
        for (int i=0;i<8;i++){
            const float4 hv = *(const float4*)&hbuf[(r0+i)*256 + (k4<<2)];
            acc[i][0]=fmaf(hv.x,w0.x,acc[i][0]); acc[i][1]=fmaf(hv.x,w0.y,acc[i][1]);
            acc[i][2]=fmaf(hv.x,w0.z,acc[i][2]); acc[i][3]=fmaf(hv.x,w0.w,acc[i][3]);
            acc[i][0]=fmaf(hv.y,w1.x,acc[i][0]); acc[i][1]=fmaf(hv.y,w1.y,acc[i][1]);
            acc[i][2]=fmaf(hv.y,w1.z,acc[i][2]); acc[i][3]=fmaf(hv.y,w1.w,acc[i][3]);
            acc[i][0]=fmaf(hv.z,w2.x,acc[i][0]); acc[i][1]=fmaf(hv.z,w2.y,acc[i][1]);
            acc[i][2]=fmaf(hv.z,w2.z,acc[i][2]); acc[i][3]=fmaf(hv.z,w2.w,acc[i][3]);
            acc[i][0]=fmaf(hv.w,w3.x,acc[i][0]); acc[i][1]=fmaf(hv.w,w3.y,acc[i][1]);
            acc[i][2]=fmaf(hv.w,w3.z,acc[i][2]); acc[i][3]=fmaf(hv.w,w3.w,acc[i][3]);
        }
    }
    // ---- bias + GELU -> h2 (xor-swizzled, same wave-private rows) ----
    {
        const float4 bv = *(const float4*)&b2[c0];
        #pragma unroll
        for (int i=0;i<8;i++){
            const int r = r0+i;
            const float a0 = gelu_exact(acc[i][0]+bv.x);
            const float a1 = gelu_exact(acc[i][1]+bv.y);
            const float a2 = gelu_exact(acc[i][2]+bv.z);
            const float a3 = gelu_exact(acc[i][3]+bv.w);
            *(float4*)&hbuf[r*256 + (c0 ^ ((r&7)<<2))] = make_float4(a0,a1,a2,a3);
        }
    }

    // ---- stage 3: logits = h2 @ W3 + b3; log_softmax; write emissions ----
    {
        const int r3  = tid >> 3;         // 0..31 (wave w covers its own rows w*8..w*8+7)
        const int cg  = tid & 7;          // 4-col group
        const int sw3 = (r3 & 7) << 2;
        float a3[4] = {0.f,0.f,0.f,0.f};
        const float4* W34 = (const float4*)W3;
        #pragma unroll 2
        for (int k4=0;k4<64;k4++){
            const float4 hv = *(const float4*)&hbuf[r3*256 + ((k4<<2) ^ sw3)];
            const float h[4] = {hv.x,hv.y,hv.z,hv.w};
            #pragma unroll
            for (int kk=0;kk<4;kk++){
                const float4 w = W34[((k4<<2)+kk)*8 + cg];
                a3[0]=fmaf(h[kk],w.x,a3[0]); a3[1]=fmaf(h[kk],w.y,a3[1]);
                a3[2]=fmaf(h[kk],w.z,a3[2]); a3[3]=fmaf(h[kk],w.w,a3[3]);
            }
        }
        const float4 b3v = ((const float4*)b3)[cg];
        a3[0]+=b3v.x; a3[1]+=b3v.y; a3[2]+=b3v.z; a3[3]+=b3v.w;
        float m = fmaxf(fmaxf(a3[0],a3[1]),fmaxf(a3[2],a3[3]));
        m = fmaxf(m,__shfl_xor(m,4)); m = fmaxf(m,__shfl_xor(m,2)); m = fmaxf(m,__shfl_xor(m,1));
        float se = expf(a3[0]-m)+expf(a3[1]-m)+expf(a3[2]-m)+expf(a3[3]-m);
        se += __shfl_xor(se,4); se += __shfl_xor(se,2); se += __shfl_xor(se,1);
        const float lz = m + logf(se);
        float4 o = make_float4(a3[0]-lz, a3[1]-lz, a3[2]-lz, a3[3]-lz);
        *(float4*)&em_out[((size_t)(row0+r3))*32 + (cg<<2)] = o;
    }
}

// ---------------- forward scan: chunked (L=64, warm=64), linear domain, per-step normalize ----------------
__global__ __launch_bounds__(256) void hmm_fwd(
    const float* __restrict__ em, const float* __restrict__ trans,
    const float* __restrict__ li, float* __restrict__ sp, float* __restrict__ LL)
{
    __shared__ float Ab[8][32];
    const int lane = threadIdx.x & 63;
    const int s = lane & 31;
    const int ci = ((threadIdx.x >> 6) << 1) | (lane >> 5);
    const int cid = (blockIdx.x << 3) + ci;   // 4096 chunks
    const int b = cid >> 7;
    const int c = cid & 127;
    const int t0 = c << 6;

    float tc[32];
    #pragma unroll
    for (int k=0;k<32;k++) tc[k] = trans[(k<<5) + s];
    float* A = Ab[ci];
    const float* emb = em + (size_t)b*(TT*SS);
    const float li_s = li[s];

    A[s] = 0.03125f;
    asm volatile("s_waitcnt lgkmcnt(0)" ::: "memory");
    __builtin_amdgcn_wave_barrier();

    float sig = 0.f;
    float araw_prev = 0.f;

    const int tws = t0 - 64;
    float pe[8];
    #pragma unroll
    for (int j=0;j<8;j++){ int tt = tws + j; tt = tt < 0 ? 0 : tt; pe[j] = emb[(tt<<5) + s]; }

    // warm-up (64 steps; c==0 runs harmless t=0 repeats, overridden at main i==0)
    #pragma unroll 1
    for (int g=0; g<8; g++){
        float ce[8];
        #pragma unroll
        for (int j=0;j<8;j++) ce[j] = pe[j];
        #pragma unroll
        for (int j=0;j<8;j++){ int tt = tws + ((g+1)<<3) + j; tt = tt < 0 ? 0 : tt; pe[j] = emb[(tt<<5) + s]; }
        #pragma unroll
        for (int j=0;j<8;j++){
            float Av[32];
            lds_read32(A, Av);
            const float sum = arr_sum32(Av);
            const float val = dot32(Av, tc);
            const float rs = 1.0f / sum;
            const float e = __expf(ce[j]);
            const float araw = val * rs * e;
            __builtin_amdgcn_wave_barrier();
            A[s] = araw;
            asm volatile("s_waitcnt lgkmcnt(0)" ::: "memory");
            __builtin_amdgcn_wave_barrier();
        }
    }

    // main (64 steps); store for step t-1 happens at step t (sum known then)
    #pragma unroll 1
    for (int g=0; g<8; g++){
        float ce[8];
        #pragma unroll
        for (int j=0;j<8;j++) ce[j] = pe[j];
        #pragma unroll
        for (int j=0;j<8;j++){ int tt = t0 + ((g+1)<<3) + j; tt = tt > (TT-1) ? (TT-1) : tt; pe[j] = emb[(tt<<5) + s]; }
        #pragma unroll
        for (int j=0;j<8;j++){
            const int i = (g<<3) + j;
            const int t = t0 + i;
            float Av[32];
            lds_read32(A, Av);
            const float sum = arr_sum32(Av);
            const float val = dot32(Av, tc);
            const float rs = 1.0f / sum;
            if (i > 0){
                sp[((size_t)b*TT + (t-1))*SS + s] = araw_prev * rs;
                sig += __logf(sum);
            }
            const float e = __expf(ce[j]);
            float araw = val * rs * e;
            if (c == 0 && i == 0) araw = __expf(li_s) * e;   // exact init alpha0
            __builtin_amdgcn_wave_barrier();
            A[s] = araw;
            asm volatile("s_waitcnt lgkmcnt(0)" ::: "memory");
            __builtin_amdgcn_wave_barrier();
            araw_prev = araw;
        }
    }
    {   // epilogue: finish last step of region
        float Av[32];
        lds_read32(A, Av);
        const float sum = arr_sum32(Av);
        const float rs = 1.0f / sum;
        sp[((size_t)b*TT + (t0+63))*SS + s] = araw_prev * rs;
        sig += __logf(sum);
    }
    if (s == 0) atomicAdd(&LL[b], sig);
}

// ---------------- Viterbi scan: chunked (L=64, warm=128), max-plus with re-centering ----------------
__global__ __launch_bounds__(256) void hmm_vit(
    const float* __restrict__ em, const float* __restrict__ lt,
    const float* __restrict__ li, unsigned char* __restrict__ bps,
    float* __restrict__ PS, int* __restrict__ last_state)
{
    __shared__ float Vb[8][32];
    const int lane = threadIdx.x & 63;
    const int s = lane & 31;
    const int ci = ((threadIdx.x >> 6) << 1) | (lane >> 5);
    const int cid = (blockIdx.x << 3) + ci;
    const int b = cid >> 7;
    const int c = cid & 127;
    const int t0 = c << 6;

    float ltc[32];
    #pragma unroll
    for (int k=0;k<32;k++) ltc[k] = lt[(k<<5) + s];
    float* V = Vb[ci];
    const float* emb = em + (size_t)b*(TT*SS);
    const float li_s = li[s];

    V[s] = 0.f;
    asm volatile("s_waitcnt lgkmcnt(0)" ::: "memory");
    __builtin_amdgcn_wave_barrier();

    float delta = 0.f;

    const int tws = t0 - 128;
    float pe[8];
    #pragma unroll
    for (int j=0;j<8;j++){ int tt = tws + j; tt = tt < 0 ? 0 : tt; pe[j] = emb[(tt<<5) + s]; }

    // warm-up (128 steps; periodic re-center, no logging)
    #pragma unroll 1
    for (int g=0; g<16; g++){
        float ce[8];
        #pragma unroll
        for (int j=0;j<8;j++) ce[j] = pe[j];
        #pragma unroll
        for (int j=0;j<8;j++){ int tt = tws + ((g+1)<<3) + j; tt = tt < 0 ? 0 : tt; pe[j] = emb[(tt<<5) + s]; }
        #pragma unroll
        for (int j=0;j<8;j++){
            float Vv[32];
            lds_read32(V, Vv);
            float b0=-3.0e38f,b1v=-3.0e38f,b2v=-3.0e38f,b3v=-3.0e38f;
            #pragma unroll
            for (int k=0;k<32;k+=4){
                b0  = fmaxf(b0,  Vv[k]+ltc[k]);
                b1v = fmaxf(b1v, Vv[k+1]+ltc[k+1]);
                b2v = fmaxf(b2v, Vv[k+2]+ltc[k+2]);
                b3v = fmaxf(b3v, Vv[k+3]+ltc[k+3]);
            }
            float v = fmaxf(fmaxf(b0,b1v),fmaxf(b2v,b3v)) + ce[j];
            if (j == 7) v -= arr_max32(Vv);
            __builtin_amdgcn_wave_barrier();
            V[s] = v;
            asm volatile("s_waitcnt lgkmcnt(0)" ::: "memory");
            __builtin_amdgcn_wave_barrier();
        }
    }
    {   // forced exact centering at warm exit (max becomes exactly 0)
        float Vv[32];
        lds_read32(V, Vv);
        const float mm = arr_max32(Vv);
        __builtin_amdgcn_wave_barrier();
        V[s] = Vv[s] - mm;
        asm volatile("s_waitcnt lgkmcnt(0)" ::: "memory");
        __builtin_amdgcn_wave_barrier();
    }

    // main (64 steps): argmax backpointers + logged re-centering every 8 steps
    #pragma unroll 1
    for (int g=0; g<8; g++){
        float ce[8];
        #pragma unroll
        for (int j=0;j<8;j++) ce[j] = pe[j];
        #pragma unroll
        for (int j=0;j<8;j++){ int tt = t0 + ((g+1)<<3) + j; tt = tt > (TT-1) ? (TT-1) : tt; pe[j] = emb[(tt<<5) + s]; }
        #pragma unroll
        for (int j=0;j<8;j++){
            const int i = (g<<3) + j;
            const int t = t0 + i;
            float Vv[32];
            lds_read32(V, Vv);
            float B0=Vv[0]+ltc[0], B1=Vv[1]+ltc[1], B2=Vv[2]+ltc[2], B3=Vv[3]+ltc[3];
            int I0=0,I1=1,I2=2,I3=3;
            #pragma unroll
            for (int k=4;k<32;k+=4){
                float q0=Vv[k]+ltc[k];     if (q0>B0){B0=q0;I0=k;}
                float q1=Vv[k+1]+ltc[k+1]; if (q1>B1){B1=q1;I1=k+1;}
                float q2=Vv[k+2]+ltc[k+2]; if (q2>B2){B2=q2;I2=k+2;}
                float q3=Vv[k+3]+ltc[k+3]; if (q3>B3){B3=q3;I3=k+3;}
            }
            float best = B0; int bi = I0;
            if (B1>best || (B1==best && I1<bi)){best=B1;bi=I1;}
            if (B2>best || (B2==best && I2<bi)){best=B2;bi=I2;}
            if (B3>best || (B3==best && I3<bi)){best=B3;bi=I3;}
            float mmc = 0.f;
            if (j == 0){ mmc = arr_max32(Vv); delta += mmc; }  // exactly 0 at i==0
            float v;
            if (c == 0 && i == 0){
                v = li_s + ce[j];                               // exact init vit0
            } else {
                v = best + ce[j] - mmc;
                bps[((size_t)b*TT + t)*SS + s] = (unsigned char)bi;
            }
            __builtin_amdgcn_wave_barrier();
            V[s] = v;
            asm volatile("s_waitcnt lgkmcnt(0)" ::: "memory");
            __builtin_amdgcn_wave_barrier();
        }
    }
    {   // epilogue: close the telescoping sum; last chunk emits last_state
        float Vv[32];
        lds_read32(V, Vv);
        const float mm = arr_max32(Vv);
        delta += mm;
        if (c == 127){
            float best = Vv[0]; int bi = 0;
            #pragma unroll
            for (int k=1;k<32;k++){ if (Vv[k] > best){ best = Vv[k]; bi = k; } }
            if (s == 0) last_state[b] = bi;
        }
        if (s == 0) atomicAdd(&PS[b], delta);
    }
}

// ---------------- backtrace phase 1: per-256-step chunk, walk all 32 end-states, record history ----------------
__global__ __launch_bounds__(64) void hmm_btc(
    const unsigned char* __restrict__ bps, unsigned char* __restrict__ pos,
    unsigned char* __restrict__ gmap)
{
    __shared__ unsigned char bp[8192];
    const int b = blockIdx.x >> 5;
    const int cb = blockIdx.x & 31;
    const int tbase = cb << 8;
    {
        const uint4* src = (const uint4*)(bps + ((size_t)b*TT + tbase)*SS);
        uint4* dst = (uint4*)bp;
        #pragma unroll
        for (int l=0;l<8;l++) dst[threadIdx.x + (l<<6)] = src[threadIdx.x + (l<<6)];
    }
    __syncthreads();
    if (threadIdx.x < 32){
        int cur = threadIdx.x;
        unsigned char* pc = pos + (((size_t)b<<5) + cb)*8192;
        #pragma unroll 1
        for (int t=255; t>=0; t--){
            pc[(t<<5) + threadIdx.x] = (unsigned char)cur;
            if ((tbase + t) >= 1) cur = bp[(t<<5) + cur];
        }
        gmap[(((b<<5) + cb)<<5) + threadIdx.x] = (unsigned char)cur;
    }
}

// ---------------- backtrace phase 2: serial boundary composition (tiny) ----------------
__global__ __launch_bounds__(256) void hmm_btb(
    const unsigned char* __restrict__ gmap, const int* __restrict__ last_state,
    unsigned char* __restrict__ e_tab)
{
    __shared__ unsigned char gl[32768];
    #pragma unroll
    for (int l=0;l<8;l++) ((uint4*)gl)[threadIdx.x + (l<<8)] = ((const uint4*)gmap)[threadIdx.x + (l<<8)];
    __syncthreads();
    if (threadIdx.x < 32){
        const int b = threadIdx.x;
        int s = last_state[b];
        #pragma unroll 1
        for (int cb=31; cb>=1; cb--){
            e_tab[(b<<5)+cb] = (unsigned char)s;
            s = gl[(((b<<5)+cb)<<5) + s];
        }
        e_tab[b<<5] = (unsigned char)s;
    }
}

// ---------------- backtrace phase 3: parallel gather of the path ----------------
__global__ __launch_bounds__(256) void hmm_btf(
    const unsigned char* __restrict__ pos, const unsigned char* __restrict__ e_tab,
    float* __restrict__ path)
{
    const int i = blockIdx.x*256 + threadIdx.x;   // over B*T
    const int b = i >> 13;
    const int t = i & (TT-1);
    const int cb = t >> 8;
    const int e = e_tab[(b<<5) + cb];
    const unsigned char v = pos[((((size_t)b<<5) + cb)<<13) + ((t & 255)<<5) + e];
    path[i] = (float)v;
}

// ---------------- launcher ----------------
extern "C" void kernel_launch(void* const* d_in, const int* in_sizes, int n_in,
                              void* d_out, int out_size, void* d_ws, size_t ws_size,
                              hipStream_t stream)
{
    const float* x   = (const float*)d_in[0];
    const float* il  = (const float*)d_in[1];
    const float* tl  = (const float*)d_in[2];
    const float* W1  = (const float*)d_in[3];
    const float* b1  = (const float*)d_in[4];
    const float* lng = (const float*)d_in[5];
    const float* lnb = (const float*)d_in[6];
    const float* W2  = (const float*)d_in[7];
    const float* b2  = (const float*)d_in[8];
    const float* W3  = (const float*)d_in[9];
    const float* b3  = (const float*)d_in[10];

    float* out   = (float*)d_out;
    float* em    = out;                    // (B,T,S)  8388608
    float* sp    = out + 8388608;          // (B,T,S)  8388608
    float* LL    = out + 16777216;         // (B,)     32
    float* trans = out + 16777248;         // (S,S)    1024
    float* path  = out + 16778272;         // (B,T)    262144
    float* PS    = out + 17040416;         // (B,)     32

    char* wsb = (char*)d_ws;
    float* lt            = (float*)(wsb);                       // 4096 B
    float* li            = (float*)(wsb + 4096);                // 128 B
    int* last_state      = (int*)(wsb + 4224);                  // 128 B
    unsigned char* e_tab = (unsigned char*)(wsb + 4352);        // 1024 B
    unsigned char* bps   = (unsigned char*)(wsb + 8192);        // 8 MiB
    unsigned char* pos   = (unsigned char*)(wsb + 8192 + 8388608);   // 8 MiB
    unsigned char* gmap  = (unsigned char*)(wsb + 8192 + 16777216);  // 32 KiB

    hmm_prep<<<1, 1024, 0, stream>>>(il, tl, trans, lt, li, LL, PS);
    hmm_mlp<<<8192, 256, 0, stream>>>(x, W1, b1, lng, lnb, W2, b2, W3, b3, em);
    hmm_fwd<<<512, 256, 0, stream>>>(em, trans, li, sp, LL);
    hmm_vit<<<512, 256, 0, stream>>>(em, lt, li, bps, PS, last_state);
    hmm_btc<<<1024, 64, 0, stream>>>(bps, pos, gmap);
    hmm_btb<<<1, 256, 0, stream>>>(gmap, last_state, e_tab);
    hmm_btf<<<1024, 256, 0, stream>>>(pos, e_tab, path);
}

// Round 4
// 1231.520 us; speedup vs baseline: 1.1647x; 1.1627x over previous
//
#include <hip/hip_runtime.h>
#include <cstdint>
#include <cstddef>

#define TT 8192
#define SS 32

// ---------------- helpers ----------------
__device__ __forceinline__ float rsum32(float v){
    v += __shfl_xor(v,16); v += __shfl_xor(v,8); v += __shfl_xor(v,4);
    v += __shfl_xor(v,2);  v += __shfl_xor(v,1); return v;
}
__device__ __forceinline__ float rmax32(float v){
    v = fmaxf(v,__shfl_xor(v,16)); v = fmaxf(v,__shfl_xor(v,8)); v = fmaxf(v,__shfl_xor(v,4));
    v = fmaxf(v,__shfl_xor(v,2));  v = fmaxf(v,__shfl_xor(v,1)); return v;
}
__device__ __forceinline__ float rsum64(float v){
    v += __shfl_xor(v,32); v += __shfl_xor(v,16); v += __shfl_xor(v,8);
    v += __shfl_xor(v,4);  v += __shfl_xor(v,2);  v += __shfl_xor(v,1); return v;
}
__device__ __forceinline__ void lds_read32(const float* p, float* d){
    #pragma unroll
    for (int k=0;k<8;k++){
        float4 v = ((const float4*)p)[k];
        d[4*k+0]=v.x; d[4*k+1]=v.y; d[4*k+2]=v.z; d[4*k+3]=v.w;
    }
}
__device__ __forceinline__ float arr_sum32(const float* a){
    float s0=0.f,s1=0.f,s2=0.f,s3=0.f;
    #pragma unroll
    for (int k=0;k<32;k+=4){ s0+=a[k]; s1+=a[k+1]; s2+=a[k+2]; s3+=a[k+3]; }
    return (s0+s1)+(s2+s3);
}
__device__ __forceinline__ float arr_max32(const float* a){
    float s0=a[0],s1=a[1],s2=a[2],s3=a[3];
    #pragma unroll
    for (int k=4;k<32;k+=4){ s0=fmaxf(s0,a[k]); s1=fmaxf(s1,a[k+1]); s2=fmaxf(s2,a[k+2]); s3=fmaxf(s3,a[k+3]); }
    return fmaxf(fmaxf(s0,s1),fmaxf(s2,s3));
}
__device__ __forceinline__ float dot32(const float* a, const float* b){
    float s0=0.f,s1=0.f,s2=0.f,s3=0.f;
    #pragma unroll
    for (int k=0;k<32;k+=4){
        s0=fmaf(a[k],b[k],s0); s1=fmaf(a[k+1],b[k+1],s1);
        s2=fmaf(a[k+2],b[k+2],s2); s3=fmaf(a[k+3],b[k+3],s3);
    }
    return (s0+s1)+(s2+s3);
}
__device__ __forceinline__ float gelu_exact(float v){
    return 0.5f*v*(1.0f + erff(v*0.70710678118654752440f));
}

// ---------------- prep: trans softmax, log_trans, log_init, zero LL/PS ----------------
__global__ __launch_bounds__(1024) void hmm_prep(
    const float* __restrict__ il, const float* __restrict__ tl,
    float* __restrict__ trans, float* __restrict__ lt, float* __restrict__ li,
    float* __restrict__ LL, float* __restrict__ PS)
{
    const int tid = threadIdx.x;          // 1024 = 32 rows x 32 cols
    const int c = tid & 31;
    const float v = tl[tid];
    const float m = rmax32(v);
    const float e = expf(v - m);
    const float ssum = rsum32(e);
    const float t = e / ssum;
    trans[tid] = t;
    lt[tid] = logf(t + 1e-10f);
    if (tid < 32){
        const float iv = il[c];
        const float m2 = rmax32(iv);
        const float e2 = expf(iv - m2);
        const float s2 = rsum32(e2);
        li[c] = logf(e2/s2 + 1e-10f);
        LL[c] = 0.f;
        PS[c] = 0.f;
    }
}

// ---------------- emission MLP v3: 2-wave blocks, 16 rows/wave, wave-private, no barriers ----------------
// VGPR cap 128 (no spill); weight L2 traffic halved vs 8-rows/wave; h1/h2 in one 16 KiB/wave
// LDS stripe, XOR-swizzled (slot ^= row&7) so stage-3 per-row reads are conflict-free.
__global__ __launch_bounds__(128, 4) void hmm_mlp(
    const float* __restrict__ x,
    const float* __restrict__ W1, const float* __restrict__ b1,
    const float* __restrict__ lng, const float* __restrict__ lnb,
    const float* __restrict__ W2, const float* __restrict__ b2,
    const float* __restrict__ W3, const float* __restrict__ b3,
    float* __restrict__ em_out)
{
    __shared__ float hbuf[8192];                 // 32 KiB: 2 waves x [16][256]
    const int tid  = threadIdx.x;
    const int lane = tid & 63;
    const int wv   = tid >> 6;                   // 0..1
    const int rowbase = (blockIdx.x << 5) + (wv << 4);   // 32 rows/block, 16/wave
    float* hb = hbuf + (wv << 12);               // wave-private 4096 floats
    const int c0 = lane << 2;                    // stage-1/2: lane owns 4 cols

    // wave-uniform x base -> scalar (SGPR) loads
    const float* xw = x + ((size_t)__builtin_amdgcn_readfirstlane(rowbase) << 7);

    float acc[16][4];
    #pragma unroll
    for (int i=0;i<16;i++){ acc[i][0]=0.f; acc[i][1]=0.f; acc[i][2]=0.f; acc[i][3]=0.f; }

    // ---- stage 1: h1 = x @ W1 (K=128) ----
    #pragma unroll 2
    for (int k4=0;k4<32;k4++){
        const float4 w0 = *(const float4*)&W1[((k4<<2)+0)*256 + c0];
        const float4 w1 = *(const float4*)&W1[((k4<<2)+1)*256 + c0];
        const float4 w2 = *(const float4*)&W1[((k4<<2)+2)*256 + c0];
        const float4 w3 = *(const float4*)&W1[((k4<<2)+3)*256 + c0];
        #pragma unroll
        for (int i=0;i<16;i++){
            const float4 xv = *(const float4*)(xw + (i<<7) + (k4<<2));
            acc[i][0]=fmaf(xv.x,w0.x,acc[i][0]); acc[i][1]=fmaf(xv.x,w0.y,acc[i][1]);
            acc[i][2]=fmaf(xv.x,w0.z,acc[i][2]); acc[i][3]=fmaf(xv.x,w0.w,acc[i][3]);
            acc[i][0]=fmaf(xv.y,w1.x,acc[i][0]); acc[i][1]=fmaf(xv.y,w1.y,acc[i][1]);
            acc[i][2]=fmaf(xv.y,w1.z,acc[i][2]); acc[i][3]=fmaf(xv.y,w1.w,acc[i][3]);
            acc[i][0]=fmaf(xv.z,w2.x,acc[i][0]); acc[i][1]=fmaf(xv.z,w2.y,acc[i][1]);
            acc[i][2]=fmaf(xv.z,w2.z,acc[i][2]); acc[i][3]=fmaf(xv.z,w2.w,acc[i][3]);
            acc[i][0]=fmaf(xv.w,w3.x,acc[i][0]); acc[i][1]=fmaf(xv.w,w3.y,acc[i][1]);
            acc[i][2]=fmaf(xv.w,w3.z,acc[i][2]); acc[i][3]=fmaf(xv.w,w3.w,acc[i][3]);
        }
    }

    // ---- bias + LayerNorm + GELU -> h1 in LDS (swizzled: slot ^= i&7) ----
    {
        const float4 bb = *(const float4*)&b1[c0];
        const float4 gg = *(const float4*)&lng[c0];
        const float4 be = *(const float4*)&lnb[c0];
        #pragma unroll
        for (int i=0;i<16;i++){
            float a0=acc[i][0]+bb.x, a1=acc[i][1]+bb.y, a2=acc[i][2]+bb.z, a3=acc[i][3]+bb.w;
            float sm = (a0+a1)+(a2+a3);
            float sq = fmaf(a0,a0,fmaf(a1,a1,fmaf(a2,a2,a3*a3)));
            sm = rsum64(sm); sq = rsum64(sq);
            const float mu   = sm*(1.f/256.f);
            const float var  = sq*(1.f/256.f) - mu*mu;
            const float rstd = rsqrtf(var + 1e-5f);
            a0 = gelu_exact((a0-mu)*rstd*gg.x + be.x);
            a1 = gelu_exact((a1-mu)*rstd*gg.y + be.y);
            a2 = gelu_exact((a2-mu)*rstd*gg.z + be.z);
            a3 = gelu_exact((a3-mu)*rstd*gg.w + be.w);
            *(float4*)&hb[(i<<8) + (c0 ^ ((i&7)<<2))] = make_float4(a0,a1,a2,a3);
        }
    }

    // ---- stage 2: h2 = gelu(h1 @ W2 + b2) (K=256); h1 via wave-uniform ds_read broadcast ----
    #pragma unroll
    for (int i=0;i<16;i++){ acc[i][0]=0.f; acc[i][1]=0.f; acc[i][2]=0.f; acc[i][3]=0.f; }
    #pragma unroll 2
    for (int k4=0;k4<64;k4++){
        const float4 w0 = *(const float4*)&W2[((k4<<2)+0)*256 + c0];
        const float4 w1 = *(const float4*)&W2[((k4<<2)+1)*256 + c0];
        const float4 w2 = *(const float4*)&W2[((k4<<2)+2)*256 + c0];
        const float4 w3 = *(const float4*)&W2[((k4<<2)+3)*256 + c0];
        #pragma unroll
        for (int i=0;i<16;i++){
            const float4 hv = *(const float4*)&hb[(i<<8) + (((k4<<2)) ^ ((i&7)<<2))];
            acc[i][0]=fmaf(hv.x,w0.x,acc[i][0]); acc[i][1]=fmaf(hv.x,w0.y,acc[i][1]);
            acc[i][2]=fmaf(hv.x,w0.z,acc[i][2]); acc[i][3]=fmaf(hv.x,w0.w,acc[i][3]);
            acc[i][0]=fmaf(hv.y,w1.x,acc[i][0]); acc[i][1]=fmaf(hv.y,w1.y,acc[i][1]);
            acc[i][2]=fmaf(hv.y,w1.z,acc[i][2]); acc[i][3]=fmaf(hv.y,w1.w,acc[i][3]);
            acc[i][0]=fmaf(hv.z,w2.x,acc[i][0]); acc[i][1]=fmaf(hv.z,w2.y,acc[i][1]);
            acc[i][2]=fmaf(hv.z,w2.z,acc[i][2]); acc[i][3]=fmaf(hv.z,w2.w,acc[i][3]);
            acc[i][0]=fmaf(hv.w,w3.x,acc[i][0]); acc[i][1]=fmaf(hv.w,w3.y,acc[i][1]);
            acc[i][2]=fmaf(hv.w,w3.z,acc[i][2]); acc[i][3]=fmaf(hv.w,w3.w,acc[i][3]);
        }
    }
    // ---- bias + GELU -> h2 overwrites h1 stripe (same swizzle) ----
    {
        const float4 bv = *(const float4*)&b2[c0];
        #pragma unroll
        for (int i=0;i<16;i++){
            const float a0 = gelu_exact(acc[i][0]+bv.x);
            const float a1 = gelu_exact(acc[i][1]+bv.y);
            const float a2 = gelu_exact(acc[i][2]+bv.z);
            const float a3 = gelu_exact(acc[i][3]+bv.w);
            *(float4*)&hb[(i<<8) + (c0 ^ ((i&7)<<2))] = make_float4(a0,a1,a2,a3);
        }
    }

    // ---- stage 3: logits = h2 @ W3 + b3; lane = (col 0..31, K-half); log_softmax ----
    {
        const int cS = lane & 31;
        const int kh = lane >> 5;                 // 0/1: K in [kh*128, kh*128+128)
        float lg[16];
        #pragma unroll
        for (int i=0;i<16;i++) lg[i] = 0.f;
        #pragma unroll 2
        for (int k4=0;k4<32;k4++){
            const int kb = (kh<<7) + (k4<<2);     // k base
            const int slot = (kb>>2);             // float4 slot index 0..63
            const float wv0 = W3[(kb+0)*32 + cS];
            const float wv1 = W3[(kb+1)*32 + cS];
            const float wv2 = W3[(kb+2)*32 + cS];
            const float wv3 = W3[(kb+3)*32 + cS];
            #pragma unroll
            for (int i=0;i<16;i++){
                const float4 hv = *(const float4*)&hb[(i<<8) + ((slot<<2) ^ ((i&7)<<2))];
                lg[i]=fmaf(hv.x,wv0,lg[i]); lg[i]=fmaf(hv.y,wv1,lg[i]);
                lg[i]=fmaf(hv.z,wv2,lg[i]); lg[i]=fmaf(hv.w,wv3,lg[i]);
            }
        }
        const float b3v = b3[cS];
        #pragma unroll
        for (int i=0;i<16;i++){
            float v = lg[i] + __shfl_xor(lg[i], 32) + b3v;   // combine K-halves
            const float m = rmax32(v);
            const float e = expf(v - m);
            const float se = rsum32(e);
            const float o = v - (m + logf(se));
            if (lane < 32) em_out[((size_t)(rowbase + i) << 5) + cS] = o;
        }
    }
}

// ---------------- forward scan: chunked (L=64, warm=64), linear domain, per-step normalize ----------------
__global__ __launch_bounds__(256) void hmm_fwd(
    const float* __restrict__ em, const float* __restrict__ trans,
    const float* __restrict__ li, float* __restrict__ sp, float* __restrict__ LL)
{
    __shared__ float Ab[8][32];
    const int lane = threadIdx.x & 63;
    const int s = lane & 31;
    const int ci = ((threadIdx.x >> 6) << 1) | (lane >> 5);
    const int cid = (blockIdx.x << 3) + ci;   // 4096 chunks
    const int b = cid >> 7;
    const int c = cid & 127;
    const int t0 = c << 6;

    float tc[32];
    #pragma unroll
    for (int k=0;k<32;k++) tc[k] = trans[(k<<5) + s];
    float* A = Ab[ci];
    const float* emb = em + (size_t)b*(TT*SS);
    const float li_s = li[s];

    A[s] = 0.03125f;
    asm volatile("s_waitcnt lgkmcnt(0)" ::: "memory");
    __builtin_amdgcn_wave_barrier();

    float sig = 0.f;
    float araw_prev = 0.f;

    const int tws = t0 - 64;
    float pe[8];
    #pragma unroll
    for (int j=0;j<8;j++){ int tt = tws + j; tt = tt < 0 ? 0 : tt; pe[j] = emb[(tt<<5) + s]; }

    // warm-up (64 steps; c==0 runs harmless t=0 repeats, overridden at main i==0)
    #pragma unroll 1
    for (int g=0; g<8; g++){
        float ce[8];
        #pragma unroll
        for (int j=0;j<8;j++) ce[j] = pe[j];
        #pragma unroll
        for (int j=0;j<8;j++){ int tt = tws + ((g+1)<<3) + j; tt = tt < 0 ? 0 : tt; pe[j] = emb[(tt<<5) + s]; }
        #pragma unroll
        for (int j=0;j<8;j++){
            float Av[32];
            lds_read32(A, Av);
            const float sum = arr_sum32(Av);
            const float val = dot32(Av, tc);
            const float rs = 1.0f / sum;
            const float e = __expf(ce[j]);
            const float araw = val * rs * e;
            __builtin_amdgcn_wave_barrier();
            A[s] = araw;
            asm volatile("s_waitcnt lgkmcnt(0)" ::: "memory");
            __builtin_amdgcn_wave_barrier();
        }
    }

    // main (64 steps); store for step t-1 happens at step t (sum known then)
    #pragma unroll 1
    for (int g=0; g<8; g++){
        float ce[8];
        #pragma unroll
        for (int j=0;j<8;j++) ce[j] = pe[j];
        #pragma unroll
        for (int j=0;j<8;j++){ int tt = t0 + ((g+1)<<3) + j; tt = tt > (TT-1) ? (TT-1) : tt; pe[j] = emb[(tt<<5) + s]; }
        #pragma unroll
        for (int j=0;j<8;j++){
            const int i = (g<<3) + j;
            const int t = t0 + i;
            float Av[32];
            lds_read32(A, Av);
            const float sum = arr_sum32(Av);
            const float val = dot32(Av, tc);
            const float rs = 1.0f / sum;
            if (i > 0){
                sp[((size_t)b*TT + (t-1))*SS + s] = araw_prev * rs;
                sig += __logf(sum);
            }
            const float e = __expf(ce[j]);
            float araw = val * rs * e;
            if (c == 0 && i == 0) araw = __expf(li_s) * e;   // exact init alpha0
            __builtin_amdgcn_wave_barrier();
            A[s] = araw;
            asm volatile("s_waitcnt lgkmcnt(0)" ::: "memory");
            __builtin_amdgcn_wave_barrier();
            araw_prev = araw;
        }
    }
    {   // epilogue: finish last step of region
        float Av[32];
        lds_read32(A, Av);
        const float sum = arr_sum32(Av);
        const float rs = 1.0f / sum;
        sp[((size_t)b*TT + (t0+63))*SS + s] = araw_prev * rs;
        sig += __logf(sum);
    }
    if (s == 0) atomicAdd(&LL[b], sig);
}

// ---------------- Viterbi scan: chunked (L=64, warm=128), max-plus with re-centering ----------------
__global__ __launch_bounds__(256) void hmm_vit(
    const float* __restrict__ em, const float* __restrict__ lt,
    const float* __restrict__ li, unsigned char* __restrict__ bps,
    float* __restrict__ PS, int* __restrict__ last_state)
{
    __shared__ float Vb[8][32];
    const int lane = threadIdx.x & 63;
    const int s = lane & 31;
    const int ci = ((threadIdx.x >> 6) << 1) | (lane >> 5);
    const int cid = (blockIdx.x << 3) + ci;
    const int b = cid >> 7;
    const int c = cid & 127;
    const int t0 = c << 6;

    float ltc[32];
    #pragma unroll
    for (int k=0;k<32;k++) ltc[k] = lt[(k<<5) + s];
    float* V = Vb[ci];
    const float* emb = em + (size_t)b*(TT*SS);
    const float li_s = li[s];

    V[s] = 0.f;
    asm volatile("s_waitcnt lgkmcnt(0)" ::: "memory");
    __builtin_amdgcn_wave_barrier();

    float delta = 0.f;

    const int tws = t0 - 128;
    float pe[8];
    #pragma unroll
    for (int j=0;j<8;j++){ int tt = tws + j; tt = tt < 0 ? 0 : tt; pe[j] = emb[(tt<<5) + s]; }

    // warm-up (128 steps; periodic re-center, no logging)
    #pragma unroll 1
    for (int g=0; g<16; g++){
        float ce[8];
        #pragma unroll
        for (int j=0;j<8;j++) ce[j] = pe[j];
        #pragma unroll
        for (int j=0;j<8;j++){ int tt = tws + ((g+1)<<3) + j; tt = tt < 0 ? 0 : tt; pe[j] = emb[(tt<<5) + s]; }
        #pragma unroll
        for (int j=0;j<8;j++){
            float Vv[32];
            lds_read32(V, Vv);
            float b0=-3.0e38f,b1v=-3.0e38f,b2v=-3.0e38f,b3v=-3.0e38f;
            #pragma unroll
            for (int k=0;k<32;k+=4){
                b0  = fmaxf(b0,  Vv[k]+ltc[k]);
                b1v = fmaxf(b1v, Vv[k+1]+ltc[k+1]);
                b2v = fmaxf(b2v, Vv[k+2]+ltc[k+2]);
                b3v = fmaxf(b3v, Vv[k+3]+ltc[k+3]);
            }
            float v = fmaxf(fmaxf(b0,b1v),fmaxf(b2v,b3v)) + ce[j];
            if (j == 7) v -= arr_max32(Vv);
            __builtin_amdgcn_wave_barrier();
            V[s] = v;
            asm volatile("s_waitcnt lgkmcnt(0)" ::: "memory");
            __builtin_amdgcn_wave_barrier();
        }
    }
    {   // forced exact centering at warm exit (max becomes exactly 0)
        float Vv[32];
        lds_read32(V, Vv);
        const float mm = arr_max32(Vv);
        __builtin_amdgcn_wave_barrier();
        V[s] = Vv[s] - mm;
        asm volatile("s_waitcnt lgkmcnt(0)" ::: "memory");
        __builtin_amdgcn_wave_barrier();
    }

    // main (64 steps): argmax backpointers + logged re-centering every 8 steps
    #pragma unroll 1
    for (int g=0; g<8; g++){
        float ce[8];
        #pragma unroll
        for (int j=0;j<8;j++) ce[j] = pe[j];
        #pragma unroll
        for (int j=0;j<8;j++){ int tt = t0 + ((g+1)<<3) + j; tt = tt > (TT-1) ? (TT-1) : tt; pe[j] = emb[(tt<<5) + s]; }
        #pragma unroll
        for (int j=0;j<8;j++){
            const int i = (g<<3) + j;
            const int t = t0 + i;
            float Vv[32];
            lds_read32(V, Vv);
            float B0=Vv[0]+ltc[0], B1=Vv[1]+ltc[1], B2=Vv[2]+ltc[2], B3=Vv[3]+ltc[3];
            int I0=0,I1=1,I2=2,I3=3;
            #pragma unroll
            for (int k=4;k<32;k+=4){
                float q0=Vv[k]+ltc[k];     if (q0>B0){B0=q0;I0=k;}
                float q1=Vv[k+1]+ltc[k+1]; if (q1>B1){B1=q1;I1=k+1;}
                float q2=Vv[k+2]+ltc[k+2]; if (q2>B2){B2=q2;I2=k+2;}
                float q3=Vv[k+3]+ltc[k+3]; if (q3>B3){B3=q3;I3=k+3;}
            }
            float best = B0; int bi = I0;
            if (B1>best || (B1==best && I1<bi)){best=B1;bi=I1;}
            if (B2>best || (B2==best && I2<bi)){best=B2;bi=I2;}
            if (B3>best || (B3==best && I3<bi)){best=B3;bi=I3;}
            float mmc = 0.f;
            if (j == 0){ mmc = arr_max32(Vv); delta += mmc; }  // exactly 0 at i==0
            float v;
            if (c == 0 && i == 0){
                v = li_s + ce[j];                               // exact init vit0
            } else {
                v = best + ce[j] - mmc;
                bps[((size_t)b*TT + t)*SS + s] = (unsigned char)bi;
            }
            __builtin_amdgcn_wave_barrier();
            V[s] = v;
            asm volatile("s_waitcnt lgkmcnt(0)" ::: "memory");
            __builtin_amdgcn_wave_barrier();
        }
    }
    {   // epilogue: close the telescoping sum; last chunk emits last_state
        float Vv[32];
        lds_read32(V, Vv);
        const float mm = arr_max32(Vv);
        delta += mm;
        if (c == 127){
            float best = Vv[0]; int bi = 0;
            #pragma unroll
            for (int k=1;k<32;k++){ if (Vv[k] > best){ best = Vv[k]; bi = k; } }
            if (s == 0) last_state[b] = bi;
        }
        if (s == 0) atomicAdd(&PS[b], delta);
    }
}

// ---------------- backtrace phase 1: per-256-step chunk, walk all 32 end-states, record history ----------------
__global__ __launch_bounds__(64) void hmm_btc(
    const unsigned char* __restrict__ bps, unsigned char* __restrict__ pos,
    unsigned char* __restrict__ gmap)
{
    __shared__ unsigned char bp[8192];
    const int b = blockIdx.x >> 5;
    const int cb = blockIdx.x & 31;
    const int tbase = cb << 8;
    {
        const uint4* src = (const uint4*)(bps + ((size_t)b*TT + tbase)*SS);
        uint4* dst = (uint4*)bp;
        #pragma unroll
        for (int l=0;l<8;l++) dst[threadIdx.x + (l<<6)] = src[threadIdx.x + (l<<6)];
    }
    __syncthreads();
    if (threadIdx.x < 32){
        int cur = threadIdx.x;
        unsigned char* pc = pos + (((size_t)b<<5) + cb)*8192;
        #pragma unroll 1
        for (int t=255; t>=0; t--){
            pc[(t<<5) + threadIdx.x] = (unsigned char)cur;
            if ((tbase + t) >= 1) cur = bp[(t<<5) + cur];
        }
        gmap[(((b<<5) + cb)<<5) + threadIdx.x] = (unsigned char)cur;
    }
}

// ---------------- backtrace phase 2: serial boundary composition (tiny) ----------------
__global__ __launch_bounds__(256) void hmm_btb(
    const unsigned char* __restrict__ gmap, const int* __restrict__ last_state,
    unsigned char* __restrict__ e_tab)
{
    __shared__ unsigned char gl[32768];
    #pragma unroll
    for (int l=0;l<8;l++) ((uint4*)gl)[threadIdx.x + (l<<8)] = ((const uint4*)gmap)[threadIdx.x + (l<<8)];
    __syncthreads();
    if (threadIdx.x < 32){
        const int b = threadIdx.x;
        int s = last_state[b];
        #pragma unroll 1
        for (int cb=31; cb>=1; cb--){
            e_tab[(b<<5)+cb] = (unsigned char)s;
            s = gl[(((b<<5)+cb)<<5) + s];
        }
        e_tab[b<<5] = (unsigned char)s;
    }
}

// ---------------- backtrace phase 3: parallel gather of the path ----------------
__global__ __launch_bounds__(256) void hmm_btf(
    const unsigned char* __restrict__ pos, const unsigned char* __restrict__ e_tab,
    float* __restrict__ path)
{
    const int i = blockIdx.x*256 + threadIdx.x;   // over B*T
    const int b = i >> 13;
    const int t = i & (TT-1);
    const int cb = t >> 8;
    const int e = e_tab[(b<<5) + cb];
    const unsigned char v = pos[((((size_t)b<<5) + cb)<<13) + ((t & 255)<<5) + e];
    path[i] = (float)v;
}

// ---------------- launcher ----------------
extern "C" void kernel_launch(void* const* d_in, const int* in_sizes, int n_in,
                              void* d_out, int out_size, void* d_ws, size_t ws_size,
                              hipStream_t stream)
{
    const float* x   = (const float*)d_in[0];
    const float* il  = (const float*)d_in[1];
    const float* tl  = (const float*)d_in[2];
    const float* W1  = (const float*)d_in[3];
    const float* b1  = (const float*)d_in[4];
    const float* lng = (const float*)d_in[5];
    const float* lnb = (const float*)d_in[6];
    const float* W2  = (const float*)d_in[7];
    const float* b2  = (const float*)d_in[8];
    const float* W3  = (const float*)d_in[9];
    const float* b3  = (const float*)d_in[10];

    float* out   = (float*)d_out;
    float* em    = out;                    // (B,T,S)  8388608
    float* sp    = out + 8388608;          // (B,T,S)  8388608
    float* LL    = out + 16777216;         // (B,)     32
    float* trans = out + 16777248;         // (S,S)    1024
    float* path  = out + 16778272;         // (B,T)    262144
    float* PS    = out + 17040416;         // (B,)     32

    char* wsb = (char*)d_ws;
    float* lt            = (float*)(wsb);                       // 4096 B
    float* li            = (float*)(wsb + 4096);                // 128 B
    int* last_state      = (int*)(wsb + 4224);                  // 128 B
    unsigned char* e_tab = (unsigned char*)(wsb + 4352);        // 1024 B
    unsigned char* bps   = (unsigned char*)(wsb + 8192);        // 8 MiB
    unsigned char* pos   = (unsigned char*)(wsb + 8192 + 8388608);   // 8 MiB
    unsigned char* gmap  = (unsigned char*)(wsb + 8192 + 16777216);  // 32 KiB

    hmm_prep<<<1, 1024, 0, stream>>>(il, tl, trans, lt, li, LL, PS);
    hmm_mlp<<<8192, 128, 0, stream>>>(x, W1, b1, lng, lnb, W2, b2, W3, b3, em);
    hmm_fwd<<<512, 256, 0, stream>>>(em, trans, li, sp, LL);
    hmm_vit<<<512, 256, 0, stream>>>(em, lt, li, bps, PS, last_state);
    hmm_btc<<<1024, 64, 0, stream>>>(bps, pos, gmap);
    hmm_btb<<<1, 256, 0, stream>>>(gmap, last_state, e_tab);
    hmm_btf<<<1024, 256, 0, stream>>>(pos, e_tab, path);
}